// Round 1
// baseline (551.050 us; speedup 1.0000x reference)
//
#include <hip/hip_runtime.h>
#include <hip/hip_bf16.h>

#define BN   64
#define MAXN 512
#define DIM  512
#define NH   8
#define NS   32
#define DHD  64
#define NN   32768      // BN*MAXN
#define NE   524288

typedef __hip_bfloat16 bf16;
using bf16x8 = __attribute__((ext_vector_type(8))) short;   // 8 bf16 (4 VGPRs)
using f32x4  = __attribute__((ext_vector_type(4))) float;

// ---- persistent device scratch (avoids ws_size assumptions) ----
__device__ int   g_cnt[NN];
__device__ int   g_cur[NN];
__device__ int   g_off[NN + 1];
__device__ int   g_csr[NE];
__device__ float g_dinv[NN];
__device__ bf16  g_agg[NN * DIM];            // 32 MB
__device__ bf16  g_kv[NN * 2 * DIM];         // 64 MB : cols 0..511 = K, 512..1023 = V
__device__ bf16  g_wkvT[2 * DIM * DIM];      // Bt for KV gemm: [1024][512]
__device__ bf16  g_woT[DIM * DIM];           // = Wo (bf16)
__device__ bf16  g_wffT[DIM * DIM];          // = Wff (bf16)
__device__ float g_biaskv[2 * DIM];
__device__ float g_q[NS * DIM];              // scaled q
__device__ bf16  g_ctx[BN * NS * DIM];
__device__ float g_tmp[BN * NS * DIM];
__device__ float g_h1[BN * NS * DIM];
__device__ bf16  g_h1b[BN * NS * DIM];

__device__ inline float bf2f(unsigned short u) {
    union { unsigned int i; float f; } x; x.i = ((unsigned int)u) << 16; return x.f;
}

// ---------------- graph preprocessing ----------------
__global__ void k_zero() {
    int i = blockIdx.x * 256 + threadIdx.x;
    if (i < NN) { g_cnt[i] = 0; g_cur[i] = 0; }
}

__global__ void k_count(const int* __restrict__ dst) {
    int e = blockIdx.x * 256 + threadIdx.x;
    if (e < NE) atomicAdd(&g_cnt[dst[e]], 1);
}

__global__ void k_scan() {
    __shared__ int part[1024];
    int t = threadIdx.x;
    int base = t * 32;
    int loc[32]; int s = 0;
#pragma unroll
    for (int i = 0; i < 32; i++) { loc[i] = g_cnt[base + i]; s += loc[i]; }
    part[t] = s; __syncthreads();
    for (int o = 1; o < 1024; o <<= 1) {
        int v = (t >= o) ? part[t - o] : 0;
        __syncthreads();
        part[t] += v;
        __syncthreads();
    }
    int ex = (t == 0) ? 0 : part[t - 1];
#pragma unroll
    for (int i = 0; i < 32; i++) { g_off[base + i] = ex; ex += loc[i]; }
    if (t == 1023) g_off[NN] = ex;
}

__global__ void k_dinv() {
    int i = blockIdx.x * 256 + threadIdx.x;
    if (i < NN) g_dinv[i] = rsqrtf(1.0f + (float)g_cnt[i]);   // self-loop included
}

__global__ void k_fill(const int* __restrict__ src, const int* __restrict__ dst) {
    int e = blockIdx.x * 256 + threadIdx.x;
    if (e < NE) {
        int d = dst[e];
        int p = atomicAdd(&g_cur[d], 1);
        g_csr[g_off[d] + p] = src[e];
    }
}

// agg[i] = dinv[i]^2 * x[i] + sum_{e:src->i} dinv[src]*dinv[i]*x[src]   (one wave per node)
__global__ __launch_bounds__(256) void k_gather(const float* __restrict__ x) {
    int wave = threadIdx.x >> 6, lane = threadIdx.x & 63;
    int node = blockIdx.x * 4 + wave;
    float di = g_dinv[node];
    const float* xr = x + (long)node * DIM;
    float acc[8];
    float w0 = di * di;
#pragma unroll
    for (int j = 0; j < 8; j++) acc[j] = xr[lane + 64 * j] * w0;
    int e0 = g_off[node], e1 = g_off[node + 1];
    for (int e = e0; e < e1; e++) {
        int sn = g_csr[e];
        float w = g_dinv[sn] * di;
        const float* xs = x + (long)sn * DIM;
#pragma unroll
        for (int j = 0; j < 8; j++) acc[j] += w * xs[lane + 64 * j];
    }
    bf16* o = g_agg + (long)node * DIM;
#pragma unroll
    for (int j = 0; j < 8; j++) o[lane + 64 * j] = __float2bfloat16(acc[j]);
}

// ---------------- weight prep ----------------
__global__ void k_prepw(const float* __restrict__ Wk, const float* __restrict__ Wv,
                        const float* __restrict__ bk, const float* __restrict__ bv,
                        const float* __restrict__ Wo, const float* __restrict__ Wff) {
    int i = blockIdx.x * 256 + threadIdx.x;        // 0 .. 2*D*D
    int c = i >> 9, k = i & 511;
    float v = (c < DIM) ? Wk[k * DIM + c] : Wv[k * DIM + (c - DIM)];
    g_wkvT[i] = __float2bfloat16(v);               // wkvT[c][k] = Wkv[k][c]
    if (i < DIM * DIM) {
        g_woT[i]  = __float2bfloat16(Wo[i]);       // Bt for ctx@Wo^T is Wo itself
        g_wffT[i] = __float2bfloat16(Wff[i]);
    }
    if (i < 2 * DIM) g_biaskv[i] = (i < DIM) ? bk[i] : bv[i - DIM];
}

// q[s][e] = (sum_d seed[s][d] * Wq[e][d]) / sqrt(DH)
__global__ void k_qproj(const float* __restrict__ seed, const float* __restrict__ Wq) {
    int i = blockIdx.x * 256 + threadIdx.x;        // 0 .. NS*DIM
    int s = i >> 9, e = i & 511;
    const float* sr = seed + s * DIM;
    const float* wr = Wq + e * DIM;
    float acc = 0.f;
    for (int d = 0; d < DIM; d += 4) {
        float4 a = *(const float4*)(sr + d);
        float4 b = *(const float4*)(wr + d);
        acc += a.x * b.x + a.y * b.y + a.z * b.z + a.w * b.w;
    }
    g_q[i] = acc * 0.125f;
}

// ---------------- MFMA GEMM: C[M][Nout] = A[M][512] * Bt[Nout][512]^T + bias ----------------
// W=0: A=g_agg (M=NN),  Bt=g_wkvT, bias=g_biaskv, out=g_kv (bf16), Nout=1024
// W=1: A=g_ctx (M=2048),Bt=g_woT,  bias=arg,      out=g_tmp (f32), Nout=512
// W=2: A=g_h1b(M=2048), Bt=g_wffT, bias=arg,      out=g_tmp (f32), Nout=512
template<int W>
__global__ __launch_bounds__(256) void k_gemm(const float* __restrict__ biasIn) {
    constexpr int Nout = (W == 0) ? 2 * DIM : DIM;
    const bf16* A  = (W == 0) ? g_agg  : (W == 1) ? g_ctx : g_h1b;
    const bf16* Bt = (W == 0) ? g_wkvT : (W == 1) ? g_woT : g_wffT;
    const float* bias = (W == 0) ? g_biaskv : biasIn;

    __shared__ bf16 As[128 * 32];
    __shared__ bf16 Bs[128 * 32];
    int tid = threadIdx.x;
    int lane = tid & 63, wave = tid >> 6;
    int wr = wave >> 1, wc = wave & 1;
    long row0 = (long)blockIdx.x * 128, col0 = (long)blockIdx.y * 128;
    f32x4 acc[4][4];
#pragma unroll
    for (int i = 0; i < 4; i++)
#pragma unroll
        for (int j = 0; j < 4; j++) acc[i][j] = (f32x4){0.f, 0.f, 0.f, 0.f};
    int srow = tid >> 1, scol = (tid & 1) * 16;
    int fr = lane & 15, fq = lane >> 4;

    for (int kt = 0; kt < DIM; kt += 32) {
        const bf16* ag = A  + (row0 + srow) * DIM + kt + scol;
        const bf16* bg = Bt + (col0 + srow) * DIM + kt + scol;
        *(int4*)(As + srow * 32 + scol)     = *(const int4*)ag;
        *(int4*)(As + srow * 32 + scol + 8) = *(const int4*)(ag + 8);
        *(int4*)(Bs + srow * 32 + scol)     = *(const int4*)bg;
        *(int4*)(Bs + srow * 32 + scol + 8) = *(const int4*)(bg + 8);
        __syncthreads();
        bf16x8 af[4], bfv[4];
#pragma unroll
        for (int mi = 0; mi < 4; mi++)
            af[mi] = *(const bf16x8*)(As + (wr * 64 + mi * 16 + fr) * 32 + fq * 8);
#pragma unroll
        for (int ni = 0; ni < 4; ni++)
            bfv[ni] = *(const bf16x8*)(Bs + (wc * 64 + ni * 16 + fr) * 32 + fq * 8);
#pragma unroll
        for (int mi = 0; mi < 4; mi++)
#pragma unroll
            for (int ni = 0; ni < 4; ni++)
                acc[mi][ni] = __builtin_amdgcn_mfma_f32_16x16x32_bf16(af[mi], bfv[ni], acc[mi][ni], 0, 0, 0);
        __syncthreads();
    }
#pragma unroll
    for (int mi = 0; mi < 4; mi++)
#pragma unroll
        for (int ni = 0; ni < 4; ni++) {
            long col = col0 + wc * 64 + ni * 16 + fr;
            float bv = bias[col];
#pragma unroll
            for (int r = 0; r < 4; r++) {
                long row = row0 + wr * 64 + mi * 16 + fq * 4 + r;
                float v = acc[mi][ni][r] + bv;
                if constexpr (W == 0) g_kv[row * Nout + col] = __float2bfloat16(v);
                else                  g_tmp[row * Nout + col] = v;
            }
        }
}

// ---------------- attention: one block per (b,h) ----------------
__global__ __launch_bounds__(256) void k_attn() {
    __shared__ float qs[NS * DHD];      // 8 KB
    __shared__ float sc[NS * MAXN];     // 64 KB
    __shared__ float rs[NS];
    int b = blockIdx.x >> 3, h = blockIdx.x & 7;
    int tid = threadIdx.x;

    for (int i = tid; i < NS * DHD; i += 256) {
        int s = i >> 6, dh = i & 63;
        qs[i] = g_q[s * DIM + h * DHD + dh];
    }
    __syncthreads();

    const unsigned short* Kb = (const unsigned short*)g_kv + (long)b * MAXN * (2 * DIM) + h * DHD;
    // phase 1: scores
    int n0 = (tid & 127) * 4;
    int sb = (tid >> 7) * 4;
    for (int so = 0; so < 32; so += 8) {
        int s0 = sb + so;
        float acc[4][4];
#pragma unroll
        for (int i = 0; i < 4; i++)
#pragma unroll
            for (int j = 0; j < 4; j++) acc[i][j] = 0.f;
        for (int dh = 0; dh < DHD; dh += 4) {
            float4 qv[4];
#pragma unroll
            for (int i = 0; i < 4; i++) qv[i] = *(const float4*)&qs[(s0 + i) * DHD + dh];
#pragma unroll
            for (int j = 0; j < 4; j++) {
                ushort4 kb = *(const ushort4*)(Kb + (long)(n0 + j) * (2 * DIM) + dh);
                float k0 = bf2f(kb.x), k1 = bf2f(kb.y), k2 = bf2f(kb.z), k3 = bf2f(kb.w);
#pragma unroll
                for (int i = 0; i < 4; i++)
                    acc[i][j] += qv[i].x * k0 + qv[i].y * k1 + qv[i].z * k2 + qv[i].w * k3;
            }
        }
#pragma unroll
        for (int i = 0; i < 4; i++)
            *(float4*)&sc[(s0 + i) * MAXN + n0] = make_float4(acc[i][0], acc[i][1], acc[i][2], acc[i][3]);
    }
    __syncthreads();

    // phase 2: softmax (4 waves x 8 rows)
    int w = tid >> 6, l = tid & 63;
    for (int r = 0; r < 8; r++) {
        int row = w * 8 + r;
        float v[8]; float m = -1e30f;
#pragma unroll
        for (int k = 0; k < 8; k++) { v[k] = sc[row * MAXN + l + 64 * k]; m = fmaxf(m, v[k]); }
#pragma unroll
        for (int o = 32; o > 0; o >>= 1) m = fmaxf(m, __shfl_xor(m, o));
        float sum = 0.f;
#pragma unroll
        for (int k = 0; k < 8; k++) { v[k] = __expf(v[k] - m); sum += v[k]; }
#pragma unroll
        for (int o = 32; o > 0; o >>= 1) sum += __shfl_xor(sum, o);
#pragma unroll
        for (int k = 0; k < 8; k++) sc[row * MAXN + l + 64 * k] = v[k];
        if (l == 0) rs[row] = 1.0f / sum;
    }
    __syncthreads();

    // phase 3: PV
    const unsigned short* Vb = (const unsigned short*)g_kv + (long)b * MAXN * (2 * DIM) + DIM + h * DHD;
    int dh0 = (tid & 15) * 4;
    int s0 = (tid >> 4) * 2;
    float a0[4] = {0, 0, 0, 0}, a1[4] = {0, 0, 0, 0};
    for (int n = 0; n < MAXN; n++) {
        float p0 = sc[s0 * MAXN + n], p1 = sc[(s0 + 1) * MAXN + n];
        ushort4 vb = *(const ushort4*)(Vb + (long)n * (2 * DIM) + dh0);
        float f0 = bf2f(vb.x), f1 = bf2f(vb.y), f2 = bf2f(vb.z), f3 = bf2f(vb.w);
        a0[0] += p0 * f0; a0[1] += p0 * f1; a0[2] += p0 * f2; a0[3] += p0 * f3;
        a1[0] += p1 * f0; a1[1] += p1 * f1; a1[2] += p1 * f2; a1[3] += p1 * f3;
    }
    float r0 = rs[s0], r1 = rs[s0 + 1];
    bf16* c0 = g_ctx + ((long)(b * NS + s0)) * DIM + h * DHD + dh0;
    bf16* c1 = c0 + DIM;
#pragma unroll
    for (int j = 0; j < 4; j++) {
        c0[j] = __float2bfloat16(a0[j] * r0);
        c1[j] = __float2bfloat16(a1[j] * r1);
    }
}

// ---------------- layernorms ----------------
__device__ inline float blockReduceSum(float v, float* red, int tid) {
#pragma unroll
    for (int o = 32; o > 0; o >>= 1) v += __shfl_xor(v, o);
    __syncthreads();
    if ((tid & 63) == 0) red[tid >> 6] = v;
    __syncthreads();
    return red[0] + red[1] + red[2] + red[3];
}

__global__ __launch_bounds__(256) void k_ln1(const float* __restrict__ seed,
                                             const float* __restrict__ gamma,
                                             const float* __restrict__ beta) {
    __shared__ float red[4];
    int r = blockIdx.x, t = threadIdx.x;
    int s = r & 31;
    long base = (long)r * DIM;
    float v0 = g_tmp[base + t] + seed[s * DIM + t];
    float v1 = g_tmp[base + 256 + t] + seed[s * DIM + 256 + t];
    float mean = blockReduceSum(v0 + v1, red, t) * (1.0f / DIM);
    float d0 = v0 - mean, d1 = v1 - mean;
    float var = blockReduceSum(d0 * d0 + d1 * d1, red, t) * (1.0f / DIM);
    float ri = rsqrtf(var + 1e-5f);
    float o0 = d0 * ri * gamma[t] + beta[t];
    float o1 = d1 * ri * gamma[256 + t] + beta[256 + t];
    g_h1[base + t] = o0; g_h1[base + 256 + t] = o1;
    g_h1b[base + t] = __float2bfloat16(o0);
    g_h1b[base + 256 + t] = __float2bfloat16(o1);
}

__global__ __launch_bounds__(256) void k_ln2(const float* __restrict__ gamma,
                                             const float* __restrict__ beta,
                                             float* __restrict__ out) {
    __shared__ float red[4];
    int r = blockIdx.x, t = threadIdx.x;
    long base = (long)r * DIM;
    float v0 = g_tmp[base + t] + g_h1[base + t];
    float v1 = g_tmp[base + 256 + t] + g_h1[base + 256 + t];
    float mean = blockReduceSum(v0 + v1, red, t) * (1.0f / DIM);
    float d0 = v0 - mean, d1 = v1 - mean;
    float var = blockReduceSum(d0 * d0 + d1 * d1, red, t) * (1.0f / DIM);
    float ri = rsqrtf(var + 1e-5f);
    out[base + t] = d0 * ri * gamma[t] + beta[t];
    out[base + 256 + t] = d1 * ri * gamma[256 + t] + beta[256 + t];
}

// ---------------- launch ----------------
extern "C" void kernel_launch(void* const* d_in, const int* in_sizes, int n_in,
                              void* d_out, int out_size, void* d_ws, size_t ws_size,
                              hipStream_t stream) {
    (void)in_sizes; (void)n_in; (void)out_size; (void)d_ws; (void)ws_size;
    const float* x    = (const float*)d_in[1];
    const int*   ei   = (const int*)d_in[2];
    const int*   esrc = ei;
    const int*   edst = ei + NE;
    const float* seed = (const float*)d_in[4];
    const float* Wk   = (const float*)d_in[5];
    const float* bk   = (const float*)d_in[6];
    const float* Wv   = (const float*)d_in[7];
    const float* bv   = (const float*)d_in[8];
    const float* Wq   = (const float*)d_in[9];
    const float* Wo   = (const float*)d_in[10];
    const float* bo   = (const float*)d_in[11];
    const float* Wff  = (const float*)d_in[12];
    const float* bff  = (const float*)d_in[13];
    const float* gh   = (const float*)d_in[14];
    const float* bh   = (const float*)d_in[15];
    const float* gz   = (const float*)d_in[16];
    const float* bz   = (const float*)d_in[17];
    float* out = (float*)d_out;

    k_zero <<<NN / 256, 256, 0, stream>>>();
    k_count<<<NE / 256, 256, 0, stream>>>(edst);
    k_scan <<<1, 1024, 0, stream>>>();
    k_dinv <<<NN / 256, 256, 0, stream>>>();
    k_fill <<<NE / 256, 256, 0, stream>>>(esrc, edst);
    k_gather<<<NN / 4, 256, 0, stream>>>(x);
    k_prepw<<<(2 * DIM * DIM) / 256, 256, 0, stream>>>(Wk, Wv, bk, bv, Wo, Wff);
    k_qproj<<<(NS * DIM) / 256, 256, 0, stream>>>(seed, Wq);

    dim3 g1(NN / 128, (2 * DIM) / 128);
    k_gemm<0><<<g1, 256, 0, stream>>>(nullptr);

    k_attn<<<BN * NH, 256, 0, stream>>>();

    dim3 g2((BN * NS) / 128, DIM / 128);
    k_gemm<1><<<g2, 256, 0, stream>>>(bo);
    k_ln1<<<BN * NS, 256, 0, stream>>>(seed, gh, bh);
    k_gemm<2><<<g2, 256, 0, stream>>>(bff);
    k_ln2<<<BN * NS, 256, 0, stream>>>(gz, bz, out);
}

// Round 2
// 368.426 us; speedup vs baseline: 1.4957x; 1.4957x over previous
//
#include <hip/hip_runtime.h>
#include <hip/hip_bf16.h>

#define BN   64
#define MAXN 512
#define DIM  512
#define NH   8
#define NS   32
#define DHD  64
#define NN   32768      // BN*MAXN
#define NE   524288

typedef __hip_bfloat16 bf16;
using bf16x8 = __attribute__((ext_vector_type(8))) short;   // 8 bf16 (4 VGPRs)
using f32x4  = __attribute__((ext_vector_type(4))) float;

// ---- persistent device scratch (avoids ws_size assumptions) ----
__device__ int   g_cnt[NN];
__device__ int   g_cur[NN];
__device__ int   g_off[NN + 1];
__device__ int   g_csr[NE];
__device__ float g_dinv[NN];
__device__ bf16  g_agg[NN * DIM];            // 32 MB
__device__ bf16  g_kv[NN * 2 * DIM];         // 64 MB : cols 0..511 = K, 512..1023 = V
__device__ bf16  g_wkvT[2 * DIM * DIM];      // Bt for KV gemm: [1024][512]
__device__ bf16  g_woT[DIM * DIM];           // = Wo (bf16)
__device__ bf16  g_wffT[DIM * DIM];          // = Wff (bf16)
__device__ float g_biaskv[2 * DIM];
__device__ float g_q[NS * DIM];              // scaled q (f32)
__device__ bf16  g_qb[NS * DIM];             // scaled q (bf16) for MFMA frags
__device__ bf16  g_ctx[BN * NS * DIM];
__device__ float g_tmp[BN * NS * DIM];
__device__ float g_h1[BN * NS * DIM];
__device__ bf16  g_h1b[BN * NS * DIM];

__device__ inline float bf2f(unsigned short u) {
    union { unsigned int i; float f; } x; x.i = ((unsigned int)u) << 16; return x.f;
}

// ---------------- graph preprocessing ----------------
__global__ void k_zero() {
    int i = blockIdx.x * 256 + threadIdx.x;
    if (i < NN) { g_cnt[i] = 0; g_cur[i] = 0; }
}

__global__ void k_count(const int* __restrict__ dst) {
    int e = blockIdx.x * 256 + threadIdx.x;
    if (e < NE) atomicAdd(&g_cnt[dst[e]], 1);
}

__global__ void k_scan() {
    __shared__ int part[1024];
    int t = threadIdx.x;
    int base = t * 32;
    int loc[32]; int s = 0;
#pragma unroll
    for (int i = 0; i < 32; i++) { loc[i] = g_cnt[base + i]; s += loc[i]; }
    part[t] = s; __syncthreads();
    for (int o = 1; o < 1024; o <<= 1) {
        int v = (t >= o) ? part[t - o] : 0;
        __syncthreads();
        part[t] += v;
        __syncthreads();
    }
    int ex = (t == 0) ? 0 : part[t - 1];
#pragma unroll
    for (int i = 0; i < 32; i++) { g_off[base + i] = ex; ex += loc[i]; }
    if (t == 1023) g_off[NN] = ex;
}

__global__ void k_dinv() {
    int i = blockIdx.x * 256 + threadIdx.x;
    if (i < NN) g_dinv[i] = rsqrtf(1.0f + (float)g_cnt[i]);   // self-loop included
}

__global__ void k_fill(const int* __restrict__ src, const int* __restrict__ dst) {
    int e = blockIdx.x * 256 + threadIdx.x;
    if (e < NE) {
        int d = dst[e];
        int p = atomicAdd(&g_cur[d], 1);
        g_csr[g_off[d] + p] = src[e];
    }
}

// agg[i] = dinv[i]^2 * x[i] + sum_{e:src->i} dinv[src]*dinv[i]*x[src]   (one wave per node)
__global__ __launch_bounds__(256) void k_gather(const float* __restrict__ x) {
    int wave = threadIdx.x >> 6, lane = threadIdx.x & 63;
    int node = blockIdx.x * 4 + wave;
    float di = g_dinv[node];
    const float* xr = x + (long)node * DIM;
    float acc[8];
    float w0 = di * di;
#pragma unroll
    for (int j = 0; j < 8; j++) acc[j] = xr[lane + 64 * j] * w0;
    int e0 = g_off[node], e1 = g_off[node + 1];
    for (int e = e0; e < e1; e++) {
        int sn = g_csr[e];
        float w = g_dinv[sn] * di;
        const float* xs = x + (long)sn * DIM;
#pragma unroll
        for (int j = 0; j < 8; j++) acc[j] += w * xs[lane + 64 * j];
    }
    bf16* o = g_agg + (long)node * DIM;
#pragma unroll
    for (int j = 0; j < 8; j++) o[lane + 64 * j] = __float2bfloat16(acc[j]);
}

// ---------------- weight prep ----------------
__global__ void k_prepw(const float* __restrict__ Wk, const float* __restrict__ Wv,
                        const float* __restrict__ bk, const float* __restrict__ bv,
                        const float* __restrict__ Wo, const float* __restrict__ Wff) {
    int i = blockIdx.x * 256 + threadIdx.x;        // 0 .. 2*D*D
    int c = i >> 9, k = i & 511;
    float v = (c < DIM) ? Wk[k * DIM + c] : Wv[k * DIM + (c - DIM)];
    g_wkvT[i] = __float2bfloat16(v);               // wkvT[c][k] = Wkv[k][c]
    if (i < DIM * DIM) {
        g_woT[i]  = __float2bfloat16(Wo[i]);       // Bt for ctx@Wo^T is Wo itself
        g_wffT[i] = __float2bfloat16(Wff[i]);
    }
    if (i < 2 * DIM) g_biaskv[i] = (i < DIM) ? bk[i] : bv[i - DIM];
}

// q[s][e] = (sum_d seed[s][d] * Wq[e][d]) / sqrt(DH)
__global__ void k_qproj(const float* __restrict__ seed, const float* __restrict__ Wq) {
    int i = blockIdx.x * 256 + threadIdx.x;        // 0 .. NS*DIM
    int s = i >> 9, e = i & 511;
    const float* sr = seed + s * DIM;
    const float* wr = Wq + e * DIM;
    float acc = 0.f;
    for (int d = 0; d < DIM; d += 4) {
        float4 a = *(const float4*)(sr + d);
        float4 b = *(const float4*)(wr + d);
        acc += a.x * b.x + a.y * b.y + a.z * b.z + a.w * b.w;
    }
    float qv = acc * 0.125f;
    g_q[i] = qv;
    g_qb[i] = __float2bfloat16(qv);
}

// ---------------- MFMA GEMM: C[M][Nout] = A[M][512] * Bt[Nout][512]^T + bias ----------------
template<int W>
__global__ __launch_bounds__(256) void k_gemm(const float* __restrict__ biasIn) {
    constexpr int Nout = (W == 0) ? 2 * DIM : DIM;
    const bf16* A  = (W == 0) ? g_agg  : (W == 1) ? g_ctx : g_h1b;
    const bf16* Bt = (W == 0) ? g_wkvT : (W == 1) ? g_woT : g_wffT;
    const float* bias = (W == 0) ? g_biaskv : biasIn;

    __shared__ bf16 As[128 * 32];
    __shared__ bf16 Bs[128 * 32];
    int tid = threadIdx.x;
    int lane = tid & 63, wave = tid >> 6;
    int wr = wave >> 1, wc = wave & 1;
    long row0 = (long)blockIdx.x * 128, col0 = (long)blockIdx.y * 128;
    f32x4 acc[4][4];
#pragma unroll
    for (int i = 0; i < 4; i++)
#pragma unroll
        for (int j = 0; j < 4; j++) acc[i][j] = (f32x4){0.f, 0.f, 0.f, 0.f};
    int srow = tid >> 1, scol = (tid & 1) * 16;
    int fr = lane & 15, fq = lane >> 4;

    for (int kt = 0; kt < DIM; kt += 32) {
        const bf16* ag = A  + (row0 + srow) * DIM + kt + scol;
        const bf16* bg = Bt + (col0 + srow) * DIM + kt + scol;
        *(int4*)(As + srow * 32 + scol)     = *(const int4*)ag;
        *(int4*)(As + srow * 32 + scol + 8) = *(const int4*)(ag + 8);
        *(int4*)(Bs + srow * 32 + scol)     = *(const int4*)bg;
        *(int4*)(Bs + srow * 32 + scol + 8) = *(const int4*)(bg + 8);
        __syncthreads();
        bf16x8 af[4], bfv[4];
#pragma unroll
        for (int mi = 0; mi < 4; mi++)
            af[mi] = *(const bf16x8*)(As + (wr * 64 + mi * 16 + fr) * 32 + fq * 8);
#pragma unroll
        for (int ni = 0; ni < 4; ni++)
            bfv[ni] = *(const bf16x8*)(Bs + (wc * 64 + ni * 16 + fr) * 32 + fq * 8);
#pragma unroll
        for (int mi = 0; mi < 4; mi++)
#pragma unroll
            for (int ni = 0; ni < 4; ni++)
                acc[mi][ni] = __builtin_amdgcn_mfma_f32_16x16x32_bf16(af[mi], bfv[ni], acc[mi][ni], 0, 0, 0);
        __syncthreads();
    }
#pragma unroll
    for (int mi = 0; mi < 4; mi++)
#pragma unroll
        for (int ni = 0; ni < 4; ni++) {
            long col = col0 + wc * 64 + ni * 16 + fr;
            float bv = bias[col];
#pragma unroll
            for (int r = 0; r < 4; r++) {
                long row = row0 + wr * 64 + mi * 16 + fq * 4 + r;
                float v = acc[mi][ni][r] + bv;
                if constexpr (W == 0) g_kv[row * Nout + col] = __float2bfloat16(v);
                else                  g_tmp[row * Nout + col] = v;
            }
        }
}

// ---------------- attention: MFMA + LDS staging, one block per (b,h), 8 waves ----------------
// LDS: kv tile [64 rows][72 bf16] (pad-72 -> 144B row stride: bank-uniform b128 reads)
//      sc [32][516] f32 (pad-516: bank-uniform b128 reads of P rows)
__global__ __launch_bounds__(512) void k_attn() {
    __shared__ bf16  kv[64 * 72];        // 9216 B
    __shared__ float sc[32 * 516];       // 66048 B
    __shared__ float rs[NS];
    int b = blockIdx.x >> 3, h = blockIdx.x & 7;
    int tid = threadIdx.x;
    int lane = tid & 63, w = tid >> 6;
    int fr = lane & 15, fq = lane >> 4;
    int stile = w >> 2;                  // 0/1 : this wave's s-tile (QK and PV)
    int nsub  = w & 3;                   // QK: n-subtile within 64-tile
    int dht   = w & 3;                   // PV: dh-subtile

    const unsigned short* KV = (const unsigned short*)g_kv + (long)b * MAXN * (2 * DIM) + h * DHD;
    int srow = tid >> 3;                 // 0..63
    int scol = (tid & 7) * 8;            // bf16 col, 16B chunks

    // Q fragments (register-resident, bf16 source)
    bf16x8 qf[2];
#pragma unroll
    for (int k0 = 0; k0 < 2; k0++)
        qf[k0] = *(const bf16x8*)(g_qb + (long)(stile * 16 + fr) * DIM + h * DHD + k0 * 32 + fq * 8);

    // ---- phase 1: scores = Q K^T ----
    int4 pre = *(const int4*)(KV + (long)srow * (2 * DIM) + scol);
    for (int t = 0; t < 8; t++) {
        __syncthreads();                                   // prev compute done
        *(int4*)((unsigned short*)kv + srow * 72 + scol) = pre;
        if (t < 7) pre = *(const int4*)(KV + (long)((t + 1) * 64 + srow) * (2 * DIM) + scol);
        __syncthreads();                                   // tile staged
        f32x4 acc = {0.f, 0.f, 0.f, 0.f};
#pragma unroll
        for (int k0 = 0; k0 < 2; k0++) {
            bf16x8 kf = *(const bf16x8*)(kv + (nsub * 16 + fr) * 72 + k0 * 32 + fq * 8);
            acc = __builtin_amdgcn_mfma_f32_16x16x32_bf16(qf[k0], kf, acc, 0, 0, 0);
        }
        int n = t * 64 + nsub * 16 + fr;
#pragma unroll
        for (int r = 0; r < 4; r++)
            sc[(stile * 16 + fq * 4 + r) * 516 + n] = acc[r];
    }
    __syncthreads();

    // prefetch V tile 0 (overlaps softmax)
    pre = *(const int4*)(KV + DIM + (long)srow * (2 * DIM) + scol);

    // ---- phase 2: softmax over n (wave-parallel, 4 rows/wave) ----
#pragma unroll
    for (int r = 0; r < 4; r++) {
        int row = w * 4 + r;
        int base = row * 516 + lane;
        float v[8]; float m = -1e30f;
#pragma unroll
        for (int k = 0; k < 8; k++) { v[k] = sc[base + 64 * k]; m = fmaxf(m, v[k]); }
#pragma unroll
        for (int o = 32; o > 0; o >>= 1) m = fmaxf(m, __shfl_xor(m, o));
        float sum = 0.f;
#pragma unroll
        for (int k = 0; k < 8; k++) { v[k] = __expf(v[k] - m); sum += v[k]; }
#pragma unroll
        for (int o = 32; o > 0; o >>= 1) sum += __shfl_xor(sum, o);
#pragma unroll
        for (int k = 0; k < 8; k++) sc[base + 64 * k] = v[k];
        if (lane == 0) rs[row] = 1.0f / sum;
    }

    // ---- phase 3: ctx = P V ----
    f32x4 acc3 = {0.f, 0.f, 0.f, 0.f};
    for (int t = 0; t < 8; t++) {
        __syncthreads();                                   // softmax / prev compute done
        *(int4*)((unsigned short*)kv + srow * 72 + scol) = pre;
        if (t < 7) pre = *(const int4*)(KV + DIM + (long)((t + 1) * 64 + srow) * (2 * DIM) + scol);
        __syncthreads();
        const float* Pp = sc + (stile * 16 + fr) * 516 + t * 64;
#pragma unroll
        for (int k0 = 0; k0 < 2; k0++) {
            bf16x8 pa, vb;
#pragma unroll
            for (int i = 0; i < 8; i++) {
                bf16 pb = __float2bfloat16(Pp[k0 * 32 + fq * 8 + i]);
                pa[i] = *(short*)&pb;
                vb[i] = *((const short*)kv + (k0 * 32 + fq * 8 + i) * 72 + dht * 16 + fr);
            }
            acc3 = __builtin_amdgcn_mfma_f32_16x16x32_bf16(pa, vb, acc3, 0, 0, 0);
        }
    }
    // epilogue: scale by 1/rowsum, store bf16 ctx
    int dh = dht * 16 + fr;
    bf16* cp = g_ctx + ((long)(b * NS + stile * 16 + fq * 4)) * DIM + h * DHD + dh;
#pragma unroll
    for (int r = 0; r < 4; r++) {
        int row = stile * 16 + fq * 4 + r;
        cp[(long)r * DIM] = __float2bfloat16(acc3[r] * rs[row]);
    }
}

// ---------------- layernorms ----------------
__device__ inline float blockReduceSum(float v, float* red, int tid) {
#pragma unroll
    for (int o = 32; o > 0; o >>= 1) v += __shfl_xor(v, o);
    __syncthreads();
    if ((tid & 63) == 0) red[tid >> 6] = v;
    __syncthreads();
    return red[0] + red[1] + red[2] + red[3];
}

__global__ __launch_bounds__(256) void k_ln1(const float* __restrict__ seed,
                                             const float* __restrict__ gamma,
                                             const float* __restrict__ beta) {
    __shared__ float red[4];
    int r = blockIdx.x, t = threadIdx.x;
    int s = r & 31;
    long base = (long)r * DIM;
    float v0 = g_tmp[base + t] + seed[s * DIM + t];
    float v1 = g_tmp[base + 256 + t] + seed[s * DIM + 256 + t];
    float mean = blockReduceSum(v0 + v1, red, t) * (1.0f / DIM);
    float d0 = v0 - mean, d1 = v1 - mean;
    float var = blockReduceSum(d0 * d0 + d1 * d1, red, t) * (1.0f / DIM);
    float ri = rsqrtf(var + 1e-5f);
    float o0 = d0 * ri * gamma[t] + beta[t];
    float o1 = d1 * ri * gamma[256 + t] + beta[256 + t];
    g_h1[base + t] = o0; g_h1[base + 256 + t] = o1;
    g_h1b[base + t] = __float2bfloat16(o0);
    g_h1b[base + 256 + t] = __float2bfloat16(o1);
}

__global__ __launch_bounds__(256) void k_ln2(const float* __restrict__ gamma,
                                             const float* __restrict__ beta,
                                             float* __restrict__ out) {
    __shared__ float red[4];
    int r = blockIdx.x, t = threadIdx.x;
    long base = (long)r * DIM;
    float v0 = g_tmp[base + t] + g_h1[base + t];
    float v1 = g_tmp[base + 256 + t] + g_h1[base + 256 + t];
    float mean = blockReduceSum(v0 + v1, red, t) * (1.0f / DIM);
    float d0 = v0 - mean, d1 = v1 - mean;
    float var = blockReduceSum(d0 * d0 + d1 * d1, red, t) * (1.0f / DIM);
    float ri = rsqrtf(var + 1e-5f);
    out[base + t] = d0 * ri * gamma[t] + beta[t];
    out[base + 256 + t] = d1 * ri * gamma[256 + t] + beta[256 + t];
}

// ---------------- launch ----------------
extern "C" void kernel_launch(void* const* d_in, const int* in_sizes, int n_in,
                              void* d_out, int out_size, void* d_ws, size_t ws_size,
                              hipStream_t stream) {
    (void)in_sizes; (void)n_in; (void)out_size; (void)d_ws; (void)ws_size;
    const float* x    = (const float*)d_in[1];
    const int*   ei   = (const int*)d_in[2];
    const int*   esrc = ei;
    const int*   edst = ei + NE;
    const float* seed = (const float*)d_in[4];
    const float* Wk   = (const float*)d_in[5];
    const float* bk   = (const float*)d_in[6];
    const float* Wv   = (const float*)d_in[7];
    const float* bv   = (const float*)d_in[8];
    const float* Wq   = (const float*)d_in[9];
    const float* Wo   = (const float*)d_in[10];
    const float* bo   = (const float*)d_in[11];
    const float* Wff  = (const float*)d_in[12];
    const float* bff  = (const float*)d_in[13];
    const float* gh   = (const float*)d_in[14];
    const float* bh   = (const float*)d_in[15];
    const float* gz   = (const float*)d_in[16];
    const float* bz   = (const float*)d_in[17];
    float* out = (float*)d_out;

    k_zero <<<NN / 256, 256, 0, stream>>>();
    k_count<<<NE / 256, 256, 0, stream>>>(edst);
    k_scan <<<1, 1024, 0, stream>>>();
    k_dinv <<<NN / 256, 256, 0, stream>>>();
    k_fill <<<NE / 256, 256, 0, stream>>>(esrc, edst);
    k_gather<<<NN / 4, 256, 0, stream>>>(x);
    k_prepw<<<(2 * DIM * DIM) / 256, 256, 0, stream>>>(Wk, Wv, bk, bv, Wo, Wff);
    k_qproj<<<(NS * DIM) / 256, 256, 0, stream>>>(seed, Wq);

    dim3 g1(NN / 128, (2 * DIM) / 128);
    k_gemm<0><<<g1, 256, 0, stream>>>(nullptr);

    k_attn<<<BN * NH, 512, 0, stream>>>();

    dim3 g2((BN * NS) / 128, DIM / 128);
    k_gemm<1><<<g2, 256, 0, stream>>>(bo);
    k_ln1<<<BN * NS, 256, 0, stream>>>(seed, gh, bh);
    k_gemm<2><<<g2, 256, 0, stream>>>(bff);
    k_ln2<<<BN * NS, 256, 0, stream>>>(gz, bz, out);
}

// Round 3
// 286.000 us; speedup vs baseline: 1.9267x; 1.2882x over previous
//
#include <hip/hip_runtime.h>
#include <hip/hip_bf16.h>

#define BN   64
#define MAXN 512
#define DIM  512
#define NH   8
#define NS   32
#define DHD  64
#define NN   32768      // BN*MAXN
#define NE   524288

typedef __hip_bfloat16 bf16;
using bf16x8 = __attribute__((ext_vector_type(8))) short;   // 8 bf16 (4 VGPRs)
using f32x4  = __attribute__((ext_vector_type(4))) float;

// ---- persistent device scratch (avoids ws_size assumptions) ----
__device__ int   g_cnt[NN];
__device__ int   g_cur[NN];
__device__ int   g_off[NN + 1];
__device__ int   g_csr[NE];
__device__ float g_dinv[NN];
__device__ bf16  g_xb[NN * DIM];             // 32 MB : x * dinv, bf16
__device__ bf16  g_agg[NN * DIM];            // 32 MB
__device__ bf16  g_kv[NN * 2 * DIM];         // 64 MB : cols 0..511 = K, 512..1023 = V
__device__ bf16  g_wkvT[2 * DIM * DIM];      // Bt for KV gemm: [1024][512]
__device__ bf16  g_woT[DIM * DIM];           // = Wo (bf16)
__device__ bf16  g_wffT[DIM * DIM];          // = Wff (bf16)
__device__ float g_biaskv[2 * DIM];
__device__ float g_q[NS * DIM];              // scaled q (f32)
__device__ bf16  g_qb[NS * DIM];             // scaled q (bf16) for MFMA frags
__device__ bf16  g_ctx[BN * NS * DIM];
__device__ float g_tmp[BN * NS * DIM];
__device__ float g_h1[BN * NS * DIM];
__device__ bf16  g_h1b[BN * NS * DIM];

__device__ inline float bf2f(unsigned short u) {
    union { unsigned int i; float f; } x; x.i = ((unsigned int)u) << 16; return x.f;
}

__device__ inline void gll16(const bf16* g, bf16* l) {
    __builtin_amdgcn_global_load_lds(
        (const __attribute__((address_space(1))) void*)g,
        (__attribute__((address_space(3))) void*)l, 16, 0, 0);
}

// ---------------- graph preprocessing ----------------
__global__ void k_zero() {
    int i = blockIdx.x * 256 + threadIdx.x;
    if (i < NN) { g_cnt[i] = 0; g_cur[i] = 0; }
}

__global__ void k_count(const int* __restrict__ dst) {
    int e = blockIdx.x * 256 + threadIdx.x;
    if (e < NE) atomicAdd(&g_cnt[dst[e]], 1);
}

__global__ void k_scan() {
    __shared__ int part[1024];
    int t = threadIdx.x;
    int base = t * 32;
    int loc[32]; int s = 0;
#pragma unroll
    for (int i = 0; i < 32; i++) { loc[i] = g_cnt[base + i]; s += loc[i]; }
    part[t] = s; __syncthreads();
    for (int o = 1; o < 1024; o <<= 1) {
        int v = (t >= o) ? part[t - o] : 0;
        __syncthreads();
        part[t] += v;
        __syncthreads();
    }
    int ex = (t == 0) ? 0 : part[t - 1];
#pragma unroll
    for (int i = 0; i < 32; i++) { g_off[base + i] = ex; ex += loc[i]; }
    if (t == 1023) g_off[NN] = ex;
}

__global__ void k_dinv() {
    int i = blockIdx.x * 256 + threadIdx.x;
    if (i < NN) g_dinv[i] = rsqrtf(1.0f + (float)g_cnt[i]);   // self-loop included
}

__global__ void k_fill(const int* __restrict__ src, const int* __restrict__ dst) {
    int e = blockIdx.x * 256 + threadIdx.x;
    if (e < NE) {
        int d = dst[e];
        int p = atomicAdd(&g_cur[d], 1);
        g_csr[g_off[d] + p] = src[e];
    }
}

// xb[i] = bf16(x[i] * dinv[node])  -- folds the per-source norm into the row
__global__ __launch_bounds__(256) void k_xb(const float* __restrict__ x) {
    long i = (long)(blockIdx.x * 256 + threadIdx.x) * 8;
    int node = (int)(i >> 9);
    float w = g_dinv[node];
    float4 a = *(const float4*)(x + i);
    float4 b = *(const float4*)(x + i + 4);
    float v[8] = {a.x, a.y, a.z, a.w, b.x, b.y, b.z, b.w};
    bf16x8 o;
#pragma unroll
    for (int j = 0; j < 8; j++) { bf16 t = __float2bfloat16(v[j] * w); o[j] = *(short*)&t; }
    *(bf16x8*)(g_xb + i) = o;
}

// agg[d] = bf16( dinv[d] * ( xb[d] + sum_{e:src->d} xb[src] ) )   (one wave per node)
// XCD-chunked swizzle: graphs 8g..8g+7 pinned to one XCD's L2 (xb slice = 4MB)
__global__ __launch_bounds__(256) void k_gather() {
    int bid = blockIdx.x;
    int lb = (bid & 7) * 1024 + (bid >> 3);
    int wave = threadIdx.x >> 6, lane = threadIdx.x & 63;
    int node = lb * 4 + wave;

    bf16x8 sv = ((const bf16x8*)(g_xb + (long)node * DIM))[lane];
    float acc[8];
#pragma unroll
    for (int j = 0; j < 8; j++) acc[j] = bf2f((unsigned short)sv[j]);

    int e = g_off[node], e1 = g_off[node + 1];
    for (; e + 2 <= e1; e += 2) {
        int s0 = g_csr[e], s1 = g_csr[e + 1];
        bf16x8 r0 = ((const bf16x8*)(g_xb + (long)s0 * DIM))[lane];
        bf16x8 r1 = ((const bf16x8*)(g_xb + (long)s1 * DIM))[lane];
#pragma unroll
        for (int j = 0; j < 8; j++)
            acc[j] += bf2f((unsigned short)r0[j]) + bf2f((unsigned short)r1[j]);
    }
    if (e < e1) {
        int s0 = g_csr[e];
        bf16x8 r0 = ((const bf16x8*)(g_xb + (long)s0 * DIM))[lane];
#pragma unroll
        for (int j = 0; j < 8; j++) acc[j] += bf2f((unsigned short)r0[j]);
    }
    float dd = g_dinv[node];
    bf16x8 o;
#pragma unroll
    for (int j = 0; j < 8; j++) { bf16 t = __float2bfloat16(acc[j] * dd); o[j] = *(short*)&t; }
    ((bf16x8*)(g_agg + (long)node * DIM))[lane] = o;
}

// ---------------- weight prep ----------------
__global__ void k_prepw(const float* __restrict__ Wk, const float* __restrict__ Wv,
                        const float* __restrict__ bk, const float* __restrict__ bv,
                        const float* __restrict__ Wo, const float* __restrict__ Wff) {
    int i = blockIdx.x * 256 + threadIdx.x;        // 0 .. 2*D*D
    int c = i >> 9, k = i & 511;
    float v = (c < DIM) ? Wk[k * DIM + c] : Wv[k * DIM + (c - DIM)];
    g_wkvT[i] = __float2bfloat16(v);               // wkvT[c][k] = Wkv[k][c]
    if (i < DIM * DIM) {
        g_woT[i]  = __float2bfloat16(Wo[i]);       // Bt for ctx@Wo^T is Wo itself
        g_wffT[i] = __float2bfloat16(Wff[i]);
    }
    if (i < 2 * DIM) g_biaskv[i] = (i < DIM) ? bk[i] : bv[i - DIM];
}

// q[s][e] = (sum_d seed[s][d] * Wq[e][d]) / sqrt(DH)
__global__ void k_qproj(const float* __restrict__ seed, const float* __restrict__ Wq) {
    int i = blockIdx.x * 256 + threadIdx.x;        // 0 .. NS*DIM
    int s = i >> 9, e = i & 511;
    const float* sr = seed + s * DIM;
    const float* wr = Wq + e * DIM;
    float acc = 0.f;
    for (int d = 0; d < DIM; d += 4) {
        float4 a = *(const float4*)(sr + d);
        float4 b = *(const float4*)(wr + d);
        acc += a.x * b.x + a.y * b.y + a.z * b.z + a.w * b.w;
    }
    float qv = acc * 0.125f;
    g_q[i] = qv;
    g_qb[i] = __float2bfloat16(qv);
}

// ---------------- MFMA GEMM: C[M][Nout] = A[M][512] * Bt[Nout][512]^T + bias ----------------
// Staging via global_load_lds width-16: LDS layout [128][32] bf16, linear, unpadded.
template<int W>
__global__ __launch_bounds__(256) void k_gemm(const float* __restrict__ biasIn) {
    constexpr int Nout = (W == 0) ? 2 * DIM : DIM;
    const bf16* A  = (W == 0) ? g_agg  : (W == 1) ? g_ctx : g_h1b;
    const bf16* Bt = (W == 0) ? g_wkvT : (W == 1) ? g_woT : g_wffT;
    const float* bias = (W == 0) ? g_biaskv : biasIn;

    __shared__ bf16 As[128 * 32];
    __shared__ bf16 Bs[128 * 32];
    int tid = threadIdx.x;
    int lane = tid & 63, wave = tid >> 6;
    int wr = wave >> 1, wc = wave & 1;
    long row0 = (long)blockIdx.x * 128, col0 = (long)blockIdx.y * 128;
    f32x4 acc[4][4];
#pragma unroll
    for (int i = 0; i < 4; i++)
#pragma unroll
        for (int j = 0; j < 4; j++) acc[i][j] = (f32x4){0.f, 0.f, 0.f, 0.f};
    int fr = lane & 15, fq = lane >> 4;

    // staging chunk ids: wave stages chunks [wave*128, wave*128+128) of each 8KB buffer
    // chunk u (16B) -> LDS byte u*16; row = u>>2, col = (u&3)*8 bf16
    int u0 = wave * 128 + lane;

    for (int kt = 0; kt < DIM; kt += 32) {
#pragma unroll
        for (int c = 0; c < 2; c++) {
            int u = u0 + c * 64;
            int row = u >> 2, col = (u & 3) * 8;
            gll16(A + (row0 + row) * DIM + kt + col, As + (wave * 128 + c * 64) * 8);
        }
#pragma unroll
        for (int c = 0; c < 2; c++) {
            int u = u0 + c * 64;
            int row = u >> 2, col = (u & 3) * 8;
            gll16(Bt + (col0 + row) * DIM + kt + col, Bs + (wave * 128 + c * 64) * 8);
        }
        __syncthreads();
        bf16x8 af[4], bfv[4];
#pragma unroll
        for (int mi = 0; mi < 4; mi++)
            af[mi] = *(const bf16x8*)(As + (wr * 64 + mi * 16 + fr) * 32 + fq * 8);
#pragma unroll
        for (int ni = 0; ni < 4; ni++)
            bfv[ni] = *(const bf16x8*)(Bs + (wc * 64 + ni * 16 + fr) * 32 + fq * 8);
#pragma unroll
        for (int mi = 0; mi < 4; mi++)
#pragma unroll
            for (int ni = 0; ni < 4; ni++)
                acc[mi][ni] = __builtin_amdgcn_mfma_f32_16x16x32_bf16(af[mi], bfv[ni], acc[mi][ni], 0, 0, 0);
        __syncthreads();
    }
#pragma unroll
    for (int mi = 0; mi < 4; mi++)
#pragma unroll
        for (int ni = 0; ni < 4; ni++) {
            long col = col0 + wc * 64 + ni * 16 + fr;
            float bv = bias[col];
#pragma unroll
            for (int r = 0; r < 4; r++) {
                long row = row0 + wr * 64 + mi * 16 + fq * 4 + r;
                float v = acc[mi][ni][r] + bv;
                if constexpr (W == 0) g_kv[row * Nout + col] = __float2bfloat16(v);
                else                  g_tmp[row * Nout + col] = v;
            }
        }
}

// ---------------- attention: MFMA + LDS staging, one block per (b,h), 8 waves ----------------
__global__ __launch_bounds__(512) void k_attn() {
    __shared__ bf16  kv[64 * 72];        // 9216 B
    __shared__ float sc[32 * 516];       // 66048 B
    __shared__ float rs[NS];
    int b = blockIdx.x >> 3, h = blockIdx.x & 7;
    int tid = threadIdx.x;
    int lane = tid & 63, w = tid >> 6;
    int fr = lane & 15, fq = lane >> 4;
    int stile = w >> 2;
    int nsub  = w & 3;
    int dht   = w & 3;

    const unsigned short* KV = (const unsigned short*)g_kv + (long)b * MAXN * (2 * DIM) + h * DHD;
    int srow = tid >> 3;
    int scol = (tid & 7) * 8;

    bf16x8 qf[2];
#pragma unroll
    for (int k0 = 0; k0 < 2; k0++)
        qf[k0] = *(const bf16x8*)(g_qb + (long)(stile * 16 + fr) * DIM + h * DHD + k0 * 32 + fq * 8);

    // ---- phase 1: scores = Q K^T ----
    int4 pre = *(const int4*)(KV + (long)srow * (2 * DIM) + scol);
    for (int t = 0; t < 8; t++) {
        __syncthreads();
        *(int4*)((unsigned short*)kv + srow * 72 + scol) = pre;
        if (t < 7) pre = *(const int4*)(KV + (long)((t + 1) * 64 + srow) * (2 * DIM) + scol);
        __syncthreads();
        f32x4 acc = {0.f, 0.f, 0.f, 0.f};
#pragma unroll
        for (int k0 = 0; k0 < 2; k0++) {
            bf16x8 kf = *(const bf16x8*)(kv + (nsub * 16 + fr) * 72 + k0 * 32 + fq * 8);
            acc = __builtin_amdgcn_mfma_f32_16x16x32_bf16(qf[k0], kf, acc, 0, 0, 0);
        }
        int n = t * 64 + nsub * 16 + fr;
#pragma unroll
        for (int r = 0; r < 4; r++)
            sc[(stile * 16 + fq * 4 + r) * 516 + n] = acc[r];
    }
    __syncthreads();

    pre = *(const int4*)(KV + DIM + (long)srow * (2 * DIM) + scol);

    // ---- phase 2: softmax ----
#pragma unroll
    for (int r = 0; r < 4; r++) {
        int row = w * 4 + r;
        int base = row * 516 + lane;
        float v[8]; float m = -1e30f;
#pragma unroll
        for (int k = 0; k < 8; k++) { v[k] = sc[base + 64 * k]; m = fmaxf(m, v[k]); }
#pragma unroll
        for (int o = 32; o > 0; o >>= 1) m = fmaxf(m, __shfl_xor(m, o));
        float sum = 0.f;
#pragma unroll
        for (int k = 0; k < 8; k++) { v[k] = __expf(v[k] - m); sum += v[k]; }
#pragma unroll
        for (int o = 32; o > 0; o >>= 1) sum += __shfl_xor(sum, o);
#pragma unroll
        for (int k = 0; k < 8; k++) sc[base + 64 * k] = v[k];
        if (lane == 0) rs[row] = 1.0f / sum;
    }

    // ---- phase 3: ctx = P V ----
    f32x4 acc3 = {0.f, 0.f, 0.f, 0.f};
    for (int t = 0; t < 8; t++) {
        __syncthreads();
        *(int4*)((unsigned short*)kv + srow * 72 + scol) = pre;
        if (t < 7) pre = *(const int4*)(KV + DIM + (long)((t + 1) * 64 + srow) * (2 * DIM) + scol);
        __syncthreads();
        const float* Pp = sc + (stile * 16 + fr) * 516 + t * 64;
#pragma unroll
        for (int k0 = 0; k0 < 2; k0++) {
            bf16x8 pa, vb;
#pragma unroll
            for (int i = 0; i < 8; i++) {
                bf16 pb = __float2bfloat16(Pp[k0 * 32 + fq * 8 + i]);
                pa[i] = *(short*)&pb;
                vb[i] = *((const short*)kv + (k0 * 32 + fq * 8 + i) * 72 + dht * 16 + fr);
            }
            acc3 = __builtin_amdgcn_mfma_f32_16x16x32_bf16(pa, vb, acc3, 0, 0, 0);
        }
    }
    int dh = dht * 16 + fr;
    bf16* cp = g_ctx + ((long)(b * NS + stile * 16 + fq * 4)) * DIM + h * DHD + dh;
#pragma unroll
    for (int r = 0; r < 4; r++) {
        int row = stile * 16 + fq * 4 + r;
        cp[(long)r * DIM] = __float2bfloat16(acc3[r] * rs[row]);
    }
}

// ---------------- layernorms ----------------
__device__ inline float blockReduceSum(float v, float* red, int tid) {
#pragma unroll
    for (int o = 32; o > 0; o >>= 1) v += __shfl_xor(v, o);
    __syncthreads();
    if ((tid & 63) == 0) red[tid >> 6] = v;
    __syncthreads();
    return red[0] + red[1] + red[2] + red[3];
}

__global__ __launch_bounds__(256) void k_ln1(const float* __restrict__ seed,
                                             const float* __restrict__ gamma,
                                             const float* __restrict__ beta) {
    __shared__ float red[4];
    int r = blockIdx.x, t = threadIdx.x;
    int s = r & 31;
    long base = (long)r * DIM;
    float v0 = g_tmp[base + t] + seed[s * DIM + t];
    float v1 = g_tmp[base + 256 + t] + seed[s * DIM + 256 + t];
    float mean = blockReduceSum(v0 + v1, red, t) * (1.0f / DIM);
    float d0 = v0 - mean, d1 = v1 - mean;
    float var = blockReduceSum(d0 * d0 + d1 * d1, red, t) * (1.0f / DIM);
    float ri = rsqrtf(var + 1e-5f);
    float o0 = d0 * ri * gamma[t] + beta[t];
    float o1 = d1 * ri * gamma[256 + t] + beta[256 + t];
    g_h1[base + t] = o0; g_h1[base + 256 + t] = o1;
    g_h1b[base + t] = __float2bfloat16(o0);
    g_h1b[base + 256 + t] = __float2bfloat16(o1);
}

__global__ __launch_bounds__(256) void k_ln2(const float* __restrict__ gamma,
                                             const float* __restrict__ beta,
                                             float* __restrict__ out) {
    __shared__ float red[4];
    int r = blockIdx.x, t = threadIdx.x;
    long base = (long)r * DIM;
    float v0 = g_tmp[base + t] + g_h1[base + t];
    float v1 = g_tmp[base + 256 + t] + g_h1[base + 256 + t];
    float mean = blockReduceSum(v0 + v1, red, t) * (1.0f / DIM);
    float d0 = v0 - mean, d1 = v1 - mean;
    float var = blockReduceSum(d0 * d0 + d1 * d1, red, t) * (1.0f / DIM);
    float ri = rsqrtf(var + 1e-5f);
    out[base + t] = d0 * ri * gamma[t] + beta[t];
    out[base + 256 + t] = d1 * ri * gamma[256 + t] + beta[256 + t];
}

// ---------------- launch ----------------
extern "C" void kernel_launch(void* const* d_in, const int* in_sizes, int n_in,
                              void* d_out, int out_size, void* d_ws, size_t ws_size,
                              hipStream_t stream) {
    (void)in_sizes; (void)n_in; (void)out_size; (void)d_ws; (void)ws_size;
    const float* x    = (const float*)d_in[1];
    const int*   ei   = (const int*)d_in[2];
    const int*   esrc = ei;
    const int*   edst = ei + NE;
    const float* seed = (const float*)d_in[4];
    const float* Wk   = (const float*)d_in[5];
    const float* bk   = (const float*)d_in[6];
    const float* Wv   = (const float*)d_in[7];
    const float* bv   = (const float*)d_in[8];
    const float* Wq   = (const float*)d_in[9];
    const float* Wo   = (const float*)d_in[10];
    const float* bo   = (const float*)d_in[11];
    const float* Wff  = (const float*)d_in[12];
    const float* bff  = (const float*)d_in[13];
    const float* gh   = (const float*)d_in[14];
    const float* bh   = (const float*)d_in[15];
    const float* gz   = (const float*)d_in[16];
    const float* bz   = (const float*)d_in[17];
    float* out = (float*)d_out;

    k_zero <<<NN / 256, 256, 0, stream>>>();
    k_count<<<NE / 256, 256, 0, stream>>>(edst);
    k_scan <<<1, 1024, 0, stream>>>();
    k_dinv <<<NN / 256, 256, 0, stream>>>();
    k_fill <<<NE / 256, 256, 0, stream>>>(esrc, edst);
    k_xb   <<<(NN * DIM) / (256 * 8), 256, 0, stream>>>(x);
    k_gather<<<NN / 4, 256, 0, stream>>>();
    k_prepw<<<(2 * DIM * DIM) / 256, 256, 0, stream>>>(Wk, Wv, bk, bv, Wo, Wff);
    k_qproj<<<(NS * DIM) / 256, 256, 0, stream>>>(seed, Wq);

    dim3 g1(NN / 128, (2 * DIM) / 128);
    k_gemm<0><<<g1, 256, 0, stream>>>(nullptr);

    k_attn<<<BN * NH, 512, 0, stream>>>();

    dim3 g2((BN * NS) / 128, DIM / 128);
    k_gemm<1><<<g2, 256, 0, stream>>>(bo);
    k_ln1<<<BN * NS, 256, 0, stream>>>(seed, gh, bh);
    k_gemm<2><<<g2, 256, 0, stream>>>(bff);
    k_ln2<<<BN * NS, 256, 0, stream>>>(gz, bz, out);
}

// Round 4
// 239.162 us; speedup vs baseline: 2.3041x; 1.1958x over previous
//
#include <hip/hip_runtime.h>
#include <hip/hip_bf16.h>

#define BN   64
#define MAXN 512
#define DIM  512
#define NH   8
#define NS   32
#define DHD  64
#define NN   32768      // BN*MAXN
#define NE   524288

typedef __hip_bfloat16 bf16;
using bf16x8 = __attribute__((ext_vector_type(8))) short;   // 8 bf16 (4 VGPRs)
using f32x4  = __attribute__((ext_vector_type(4))) float;

// ---- persistent device scratch (avoids ws_size assumptions) ----
__device__ int   g_cnt[NN];
__device__ int   g_cur[NN];
__device__ int   g_off[NN + 1];
__device__ int   g_csr[NE];
__device__ float g_dinv[NN];
__device__ bf16  g_xb[NN * DIM];             // 32 MB : x * dinv, bf16
__device__ bf16  g_agg[NN * DIM];            // 32 MB
__device__ bf16  g_kv[NN * 2 * DIM];         // 64 MB : cols 0..511 = K, 512..1023 = V
__device__ bf16  g_wkvT[2 * DIM * DIM];      // Bt for KV gemm: [1024][512]
__device__ bf16  g_woT[DIM * DIM];           // = Wo (bf16)
__device__ bf16  g_wffT[DIM * DIM];          // = Wff (bf16)
__device__ float g_biaskv[2 * DIM];
__device__ float g_q[NS * DIM];              // scaled q (f32)
__device__ bf16  g_qb[NS * DIM];             // scaled q (bf16) for MFMA frags
__device__ bf16  g_ctx[BN * NS * DIM];
__device__ float g_tmp[BN * NS * DIM];
__device__ float g_h1[BN * NS * DIM];
__device__ bf16  g_h1b[BN * NS * DIM];

__device__ inline float bf2f(unsigned short u) {
    union { unsigned int i; float f; } x; x.i = ((unsigned int)u) << 16; return x.f;
}

__device__ inline void gll16(const bf16* g, bf16* l) {
    __builtin_amdgcn_global_load_lds(
        (const __attribute__((address_space(1))) void*)g,
        (__attribute__((address_space(3))) void*)l, 16, 0, 0);
}

// ---------------- graph preprocessing ----------------
__global__ void k_zero() {
    int i = blockIdx.x * 256 + threadIdx.x;
    if (i < NN) { g_cnt[i] = 0; g_cur[i] = 0; }
}

__global__ void k_count(const int* __restrict__ dst) {
    int e = blockIdx.x * 256 + threadIdx.x;
    if (e < NE) atomicAdd(&g_cnt[dst[e]], 1);
}

__global__ void k_scan() {
    __shared__ int part[1024];
    int t = threadIdx.x;
    int base = t * 32;
    int loc[32]; int s = 0;
#pragma unroll
    for (int i = 0; i < 32; i++) { loc[i] = g_cnt[base + i]; s += loc[i]; }
    part[t] = s; __syncthreads();
    for (int o = 1; o < 1024; o <<= 1) {
        int v = (t >= o) ? part[t - o] : 0;
        __syncthreads();
        part[t] += v;
        __syncthreads();
    }
    int ex = (t == 0) ? 0 : part[t - 1];
#pragma unroll
    for (int i = 0; i < 32; i++) { g_off[base + i] = ex; ex += loc[i]; }
    if (t == 1023) g_off[NN] = ex;
}

__global__ void k_dinv() {
    int i = blockIdx.x * 256 + threadIdx.x;
    if (i < NN) g_dinv[i] = rsqrtf(1.0f + (float)g_cnt[i]);   // self-loop included
}

__global__ void k_fill(const int* __restrict__ src, const int* __restrict__ dst) {
    int e = blockIdx.x * 256 + threadIdx.x;
    if (e < NE) {
        int d = dst[e];
        int p = atomicAdd(&g_cur[d], 1);
        g_csr[g_off[d] + p] = src[e];
    }
}

// xb[i] = bf16(x[i] * dinv[node])  -- folds the per-source norm into the row
__global__ __launch_bounds__(256) void k_xb(const float* __restrict__ x) {
    long i = (long)(blockIdx.x * 256 + threadIdx.x) * 8;
    int node = (int)(i >> 9);
    float w = g_dinv[node];
    float4 a = *(const float4*)(x + i);
    float4 b = *(const float4*)(x + i + 4);
    float v[8] = {a.x, a.y, a.z, a.w, b.x, b.y, b.z, b.w};
    bf16x8 o;
#pragma unroll
    for (int j = 0; j < 8; j++) { bf16 t = __float2bfloat16(v[j] * w); o[j] = *(short*)&t; }
    *(bf16x8*)(g_xb + i) = o;
}

// agg[d] = bf16( dinv[d] * ( xb[d] + sum_{e:src->d} xb[src] ) )   (one wave per node)
__global__ __launch_bounds__(256) void k_gather() {
    int bid = blockIdx.x;
    int lb = (bid & 7) * 1024 + (bid >> 3);
    int wave = threadIdx.x >> 6, lane = threadIdx.x & 63;
    int node = lb * 4 + wave;

    bf16x8 sv = ((const bf16x8*)(g_xb + (long)node * DIM))[lane];
    float acc[8];
#pragma unroll
    for (int j = 0; j < 8; j++) acc[j] = bf2f((unsigned short)sv[j]);

    int e = g_off[node], e1 = g_off[node + 1];
    for (; e + 2 <= e1; e += 2) {
        int s0 = g_csr[e], s1 = g_csr[e + 1];
        bf16x8 r0 = ((const bf16x8*)(g_xb + (long)s0 * DIM))[lane];
        bf16x8 r1 = ((const bf16x8*)(g_xb + (long)s1 * DIM))[lane];
#pragma unroll
        for (int j = 0; j < 8; j++)
            acc[j] += bf2f((unsigned short)r0[j]) + bf2f((unsigned short)r1[j]);
    }
    if (e < e1) {
        int s0 = g_csr[e];
        bf16x8 r0 = ((const bf16x8*)(g_xb + (long)s0 * DIM))[lane];
#pragma unroll
        for (int j = 0; j < 8; j++) acc[j] += bf2f((unsigned short)r0[j]);
    }
    float dd = g_dinv[node];
    bf16x8 o;
#pragma unroll
    for (int j = 0; j < 8; j++) { bf16 t = __float2bfloat16(acc[j] * dd); o[j] = *(short*)&t; }
    ((bf16x8*)(g_agg + (long)node * DIM))[lane] = o;
}

// ---------------- weight prep ----------------
__global__ void k_prepw(const float* __restrict__ Wk, const float* __restrict__ Wv,
                        const float* __restrict__ bk, const float* __restrict__ bv,
                        const float* __restrict__ Wo, const float* __restrict__ Wff) {
    int i = blockIdx.x * 256 + threadIdx.x;        // 0 .. 2*D*D
    int c = i >> 9, k = i & 511;
    float v = (c < DIM) ? Wk[k * DIM + c] : Wv[k * DIM + (c - DIM)];
    g_wkvT[i] = __float2bfloat16(v);               // wkvT[c][k] = Wkv[k][c]
    if (i < DIM * DIM) {
        g_woT[i]  = __float2bfloat16(Wo[i]);       // Bt for ctx@Wo^T is Wo itself
        g_wffT[i] = __float2bfloat16(Wff[i]);
    }
    if (i < 2 * DIM) g_biaskv[i] = (i < DIM) ? bk[i] : bv[i - DIM];
}

// q[s][e] = (sum_d seed[s][d] * Wq[e][d]) / sqrt(DH)
__global__ void k_qproj(const float* __restrict__ seed, const float* __restrict__ Wq) {
    int i = blockIdx.x * 256 + threadIdx.x;        // 0 .. NS*DIM
    int s = i >> 9, e = i & 511;
    const float* sr = seed + s * DIM;
    const float* wr = Wq + e * DIM;
    float acc = 0.f;
    for (int d = 0; d < DIM; d += 4) {
        float4 a = *(const float4*)(sr + d);
        float4 b = *(const float4*)(wr + d);
        acc += a.x * b.x + a.y * b.y + a.z * b.z + a.w * b.w;
    }
    float qv = acc * 0.125f;
    g_q[i] = qv;
    g_qb[i] = __float2bfloat16(qv);
}

// ---------------- MFMA GEMM: C[M][Nout] = A[M][512] * Bt[Nout][512]^T + bias ----------------
// global_load_lds width-16 staging, double-buffered LDS, one barrier per K-step.
// T2 swizzle (gll-compatible, rule #21): LDS dest linear; the 16B chunk c of row r
// holds global chunk (c ^ ((r>>1)&3)); fragment reads XOR the same term back.
template<int W>
__global__ __launch_bounds__(256) void k_gemm(const float* __restrict__ biasIn) {
    constexpr int Nout = (W == 0) ? 2 * DIM : DIM;
    const bf16* A  = (W == 0) ? g_agg  : (W == 1) ? g_ctx : g_h1b;
    const bf16* Bt = (W == 0) ? g_wkvT : (W == 1) ? g_woT : g_wffT;
    const float* bias = (W == 0) ? g_biaskv : biasIn;

    __shared__ bf16 As[2][128 * 32];
    __shared__ bf16 Bs[2][128 * 32];
    int tid = threadIdx.x;
    int lane = tid & 63, wave = tid >> 6;
    int wr = wave >> 1, wc = wave & 1;
    long row0 = (long)blockIdx.x * 128, col0 = (long)blockIdx.y * 128;
    f32x4 acc[4][4];
#pragma unroll
    for (int i = 0; i < 4; i++)
#pragma unroll
        for (int j = 0; j < 4; j++) acc[i][j] = (f32x4){0.f, 0.f, 0.f, 0.f};
    int fr = lane & 15, fq = lane >> 4;
    int sw = (fr >> 1) & 3;                       // read-side swizzle term (row-dependent)
    int rchunk = (fq ^ sw) * 8;                   // swizzled 16B chunk within the 64B row

    // staging: thread handles chunks u0, u0+64 of each 512-chunk buffer
    int u0 = wave * 128 + lane;
    int s_row[2], s_col[2];
#pragma unroll
    for (int c = 0; c < 2; c++) {
        int u = u0 + c * 64;
        int row = u >> 2, cc = u & 3;
        s_row[c] = row;
        s_col[c] = (cc ^ ((row >> 1) & 3)) * 8;   // pre-swizzled global source chunk
    }

    auto stage = [&](int buf, int kt) {
#pragma unroll
        for (int c = 0; c < 2; c++)
            gll16(A + (row0 + s_row[c]) * DIM + kt + s_col[c], As[buf] + (u0 + c * 64) * 8);
#pragma unroll
        for (int c = 0; c < 2; c++)
            gll16(Bt + (col0 + s_row[c]) * DIM + kt + s_col[c], Bs[buf] + (u0 + c * 64) * 8);
    };

    stage(0, 0);
    __syncthreads();

    for (int kt = 0; kt < DIM; kt += 32) {
        int buf = (kt >> 5) & 1;
        if (kt + 32 < DIM) stage(buf ^ 1, kt + 32);
        bf16x8 af[4], bfv[4];
#pragma unroll
        for (int mi = 0; mi < 4; mi++)
            af[mi] = *(const bf16x8*)(As[buf] + (wr * 64 + mi * 16 + fr) * 32 + rchunk);
#pragma unroll
        for (int ni = 0; ni < 4; ni++)
            bfv[ni] = *(const bf16x8*)(Bs[buf] + (wc * 64 + ni * 16 + fr) * 32 + rchunk);
#pragma unroll
        for (int mi = 0; mi < 4; mi++)
#pragma unroll
            for (int ni = 0; ni < 4; ni++)
                acc[mi][ni] = __builtin_amdgcn_mfma_f32_16x16x32_bf16(af[mi], bfv[ni], acc[mi][ni], 0, 0, 0);
        __syncthreads();   // drains staging loads for buf^1 AND protects buf for overwrite
    }
#pragma unroll
    for (int mi = 0; mi < 4; mi++)
#pragma unroll
        for (int ni = 0; ni < 4; ni++) {
            long col = col0 + wc * 64 + ni * 16 + fr;
            float bv = bias[col];
#pragma unroll
            for (int r = 0; r < 4; r++) {
                long row = row0 + wr * 64 + mi * 16 + fq * 4 + r;
                float v = acc[mi][ni][r] + bv;
                if constexpr (W == 0) g_kv[row * Nout + col] = __float2bfloat16(v);
                else                  g_tmp[row * Nout + col] = v;
            }
        }
}

// ---------------- attention: MFMA + LDS staging, one block per (b,h), 8 waves ----------------
__global__ __launch_bounds__(512) void k_attn() {
    __shared__ bf16  kv[64 * 72];        // 9216 B
    __shared__ float sc[32 * 516];       // 66048 B
    __shared__ float rs[NS];
    int b = blockIdx.x >> 3, h = blockIdx.x & 7;
    int tid = threadIdx.x;
    int lane = tid & 63, w = tid >> 6;
    int fr = lane & 15, fq = lane >> 4;
    int stile = w >> 2;
    int nsub  = w & 3;
    int dht   = w & 3;

    const unsigned short* KV = (const unsigned short*)g_kv + (long)b * MAXN * (2 * DIM) + h * DHD;
    int srow = tid >> 3;
    int scol = (tid & 7) * 8;

    bf16x8 qf[2];
#pragma unroll
    for (int k0 = 0; k0 < 2; k0++)
        qf[k0] = *(const bf16x8*)(g_qb + (long)(stile * 16 + fr) * DIM + h * DHD + k0 * 32 + fq * 8);

    // ---- phase 1: scores = Q K^T ----
    int4 pre = *(const int4*)(KV + (long)srow * (2 * DIM) + scol);
    for (int t = 0; t < 8; t++) {
        __syncthreads();
        *(int4*)((unsigned short*)kv + srow * 72 + scol) = pre;
        if (t < 7) pre = *(const int4*)(KV + (long)((t + 1) * 64 + srow) * (2 * DIM) + scol);
        __syncthreads();
        f32x4 acc = {0.f, 0.f, 0.f, 0.f};
#pragma unroll
        for (int k0 = 0; k0 < 2; k0++) {
            bf16x8 kf = *(const bf16x8*)(kv + (nsub * 16 + fr) * 72 + k0 * 32 + fq * 8);
            acc = __builtin_amdgcn_mfma_f32_16x16x32_bf16(qf[k0], kf, acc, 0, 0, 0);
        }
        int n = t * 64 + nsub * 16 + fr;
#pragma unroll
        for (int r = 0; r < 4; r++)
            sc[(stile * 16 + fq * 4 + r) * 516 + n] = acc[r];
    }
    __syncthreads();

    pre = *(const int4*)(KV + DIM + (long)srow * (2 * DIM) + scol);

    // ---- phase 2: softmax ----
#pragma unroll
    for (int r = 0; r < 4; r++) {
        int row = w * 4 + r;
        int base = row * 516 + lane;
        float v[8]; float m = -1e30f;
#pragma unroll
        for (int k = 0; k < 8; k++) { v[k] = sc[base + 64 * k]; m = fmaxf(m, v[k]); }
#pragma unroll
        for (int o = 32; o > 0; o >>= 1) m = fmaxf(m, __shfl_xor(m, o));
        float sum = 0.f;
#pragma unroll
        for (int k = 0; k < 8; k++) { v[k] = __expf(v[k] - m); sum += v[k]; }
#pragma unroll
        for (int o = 32; o > 0; o >>= 1) sum += __shfl_xor(sum, o);
#pragma unroll
        for (int k = 0; k < 8; k++) sc[base + 64 * k] = v[k];
        if (lane == 0) rs[row] = 1.0f / sum;
    }

    // ---- phase 3: ctx = P V ----
    f32x4 acc3 = {0.f, 0.f, 0.f, 0.f};
    for (int t = 0; t < 8; t++) {
        __syncthreads();
        *(int4*)((unsigned short*)kv + srow * 72 + scol) = pre;
        if (t < 7) pre = *(const int4*)(KV + DIM + (long)((t + 1) * 64 + srow) * (2 * DIM) + scol);
        __syncthreads();
        const float* Pp = sc + (stile * 16 + fr) * 516 + t * 64;
#pragma unroll
        for (int k0 = 0; k0 < 2; k0++) {
            bf16x8 pa, vb;
#pragma unroll
            for (int i = 0; i < 8; i++) {
                bf16 pb = __float2bfloat16(Pp[k0 * 32 + fq * 8 + i]);
                pa[i] = *(short*)&pb;
                vb[i] = *((const short*)kv + (k0 * 32 + fq * 8 + i) * 72 + dht * 16 + fr);
            }
            acc3 = __builtin_amdgcn_mfma_f32_16x16x32_bf16(pa, vb, acc3, 0, 0, 0);
        }
    }
    int dh = dht * 16 + fr;
    bf16* cp = g_ctx + ((long)(b * NS + stile * 16 + fq * 4)) * DIM + h * DHD + dh;
#pragma unroll
    for (int r = 0; r < 4; r++) {
        int row = stile * 16 + fq * 4 + r;
        cp[(long)r * DIM] = __float2bfloat16(acc3[r] * rs[row]);
    }
}

// ---------------- layernorms ----------------
__device__ inline float blockReduceSum(float v, float* red, int tid) {
#pragma unroll
    for (int o = 32; o > 0; o >>= 1) v += __shfl_xor(v, o);
    __syncthreads();
    if ((tid & 63) == 0) red[tid >> 6] = v;
    __syncthreads();
    return red[0] + red[1] + red[2] + red[3];
}

__global__ __launch_bounds__(256) void k_ln1(const float* __restrict__ seed,
                                             const float* __restrict__ gamma,
                                             const float* __restrict__ beta) {
    __shared__ float red[4];
    int r = blockIdx.x, t = threadIdx.x;
    int s = r & 31;
    long base = (long)r * DIM;
    float v0 = g_tmp[base + t] + seed[s * DIM + t];
    float v1 = g_tmp[base + 256 + t] + seed[s * DIM + 256 + t];
    float mean = blockReduceSum(v0 + v1, red, t) * (1.0f / DIM);
    float d0 = v0 - mean, d1 = v1 - mean;
    float var = blockReduceSum(d0 * d0 + d1 * d1, red, t) * (1.0f / DIM);
    float ri = rsqrtf(var + 1e-5f);
    float o0 = d0 * ri * gamma[t] + beta[t];
    float o1 = d1 * ri * gamma[256 + t] + beta[256 + t];
    g_h1[base + t] = o0; g_h1[base + 256 + t] = o1;
    g_h1b[base + t] = __float2bfloat16(o0);
    g_h1b[base + 256 + t] = __float2bfloat16(o1);
}

__global__ __launch_bounds__(256) void k_ln2(const float* __restrict__ gamma,
                                             const float* __restrict__ beta,
                                             float* __restrict__ out) {
    __shared__ float red[4];
    int r = blockIdx.x, t = threadIdx.x;
    long base = (long)r * DIM;
    float v0 = g_tmp[base + t] + g_h1[base + t];
    float v1 = g_tmp[base + 256 + t] + g_h1[base + 256 + t];
    float mean = blockReduceSum(v0 + v1, red, t) * (1.0f / DIM);
    float d0 = v0 - mean, d1 = v1 - mean;
    float var = blockReduceSum(d0 * d0 + d1 * d1, red, t) * (1.0f / DIM);
    float ri = rsqrtf(var + 1e-5f);
    out[base + t] = d0 * ri * gamma[t] + beta[t];
    out[base + 256 + t] = d1 * ri * gamma[256 + t] + beta[256 + t];
}

// ---------------- launch ----------------
extern "C" void kernel_launch(void* const* d_in, const int* in_sizes, int n_in,
                              void* d_out, int out_size, void* d_ws, size_t ws_size,
                              hipStream_t stream) {
    (void)in_sizes; (void)n_in; (void)out_size; (void)d_ws; (void)ws_size;
    const float* x    = (const float*)d_in[1];
    const int*   ei   = (const int*)d_in[2];
    const int*   esrc = ei;
    const int*   edst = ei + NE;
    const float* seed = (const float*)d_in[4];
    const float* Wk   = (const float*)d_in[5];
    const float* bk   = (const float*)d_in[6];
    const float* Wv   = (const float*)d_in[7];
    const float* bv   = (const float*)d_in[8];
    const float* Wq   = (const float*)d_in[9];
    const float* Wo   = (const float*)d_in[10];
    const float* bo   = (const float*)d_in[11];
    const float* Wff  = (const float*)d_in[12];
    const float* bff  = (const float*)d_in[13];
    const float* gh   = (const float*)d_in[14];
    const float* bh   = (const float*)d_in[15];
    const float* gz   = (const float*)d_in[16];
    const float* bz   = (const float*)d_in[17];
    float* out = (float*)d_out;

    k_zero <<<NN / 256, 256, 0, stream>>>();
    k_count<<<NE / 256, 256, 0, stream>>>(edst);
    k_scan <<<1, 1024, 0, stream>>>();
    k_dinv <<<NN / 256, 256, 0, stream>>>();
    k_fill <<<NE / 256, 256, 0, stream>>>(esrc, edst);
    k_xb   <<<(NN * DIM) / (256 * 8), 256, 0, stream>>>(x);
    k_gather<<<NN / 4, 256, 0, stream>>>();
    k_prepw<<<(2 * DIM * DIM) / 256, 256, 0, stream>>>(Wk, Wv, bk, bv, Wo, Wff);
    k_qproj<<<(NS * DIM) / 256, 256, 0, stream>>>(seed, Wq);

    dim3 g1(NN / 128, (2 * DIM) / 128);
    k_gemm<0><<<g1, 256, 0, stream>>>(nullptr);

    k_attn<<<BN * NH, 512, 0, stream>>>();

    dim3 g2((BN * NS) / 128, DIM / 128);
    k_gemm<1><<<g2, 256, 0, stream>>>(bo);
    k_ln1<<<BN * NS, 256, 0, stream>>>(seed, gh, bh);
    k_gemm<2><<<g2, 256, 0, stream>>>(bff);
    k_ln2<<<BN * NS, 256, 0, stream>>>(gz, bz, out);
}